// Round 6
// baseline (753.093 us; speedup 1.0000x reference)
//
#include <hip/hip_runtime.h>

// 16-qubit, depth-4, batch-512 statevector simulator — 5-sweep, packed-FP32.
// State: 512 x 65536 complex64 = 256 MiB in d_ws.
// Reference qubit q <-> flat-index bit beta = 15-q.
// Memory layout per batch: amp with basis index g stored at m = (g>>3) | ((g&7)<<13).
//
// Partition A (blocks fix g bits 0..2): local j = m bits 0..12, j_b = g_{b+3}.
// Partition B (blocks fix g bits 12..14): local d: d0..8 = g3..11, d9 = g15,
//   d10..12 = g0..2.
//
// Chain perm (16 CNOTs) = main (rows 3..14, A-local) o tail (rows 15,0,1,2,
// B-local, as register rename permB).  KEY COMMUTATIONS (this revision):
//   gates on g12..14 (qubits q3,q2,q1) commute with tail (bits 15,0..3) and
//   with B's 13 gates (bits 0..11,15) -> layer-(l+1)'s 3 A-gates can be
//   applied inside A-sweep l right after main(l) (dest bits D9..11 are
//   register-local there).  Consequently B(3) finishes ALL gates and the
//   final chain3 relabel + expZ fold into its epilogue (suffix-parity signs,
//   6 buckets) — no state store, no final read sweep.
// Schedule (5 sweeps):
//   1. qc_B1_gen:   analytic gen (L0+chain0 folded) + L1 x13.        [W only]
//   2. qc_A_mid:    L1 q3,q2,q1 + main1 + L2 q3,q2,q1 (stolen).      [RW]
//   3. qc_B_heavy:  tail1 + L2 x13.                                  [RW]
//   4. qc_A_mid:    main2 + L3 q3,q2,q1 (stolen).                    [RW]
//   5. qc_B_final:  tail2 + L3 x13 + chain3-relabel expZ.            [R only]

#define NQ 16
#define TPB 256

typedef float __attribute__((ext_vector_type(2))) f2;   // (re, im)

__device__ __forceinline__ f2 f2s(float s) { return (f2){s, s}; }

// a (*) b  (complex mul, packed: pk_mul + pk_fma)
__device__ __forceinline__ f2 cmulpk(f2 a, f2 b) {
    f2 bs = { -b.y, b.x };
    f2 r = f2s(a.x) * b;
    return __builtin_elementwise_fma(f2s(a.y), bs, r);
}

// U = RY(t2) * RX(t1) * RZ(t0), row-major [u00,u01,u10,u11]
__device__ __forceinline__ void computeU(const float* params, int layer, int q, f2* U) {
    const float* p = params + (layer*NQ + q)*3;
    float s0, c0, s1, c1, s2, c2;
    sincosf(0.5f*p[0], &s0, &c0);
    sincosf(0.5f*p[1], &s1, &c1);
    sincosf(0.5f*p[2], &s2, &c2);
    f2 m00 = { c1*c0, -c1*s0};
    f2 m01 = { s1*s0, -s1*c0};
    f2 m10 = {-s1*s0, -s1*c0};
    f2 m11 = { c1*c0,  c1*s0};
    U[0] = c2*m00 - s2*m10;
    U[1] = c2*m01 - s2*m11;
    U[2] = s2*m00 + c2*m10;
    U[3] = s2*m01 + c2*m11;
}

// 1q gate on register array A[N], pairing a <-> a|MASK.  8 packed ops/pair.
template<int MASK, int N>
__device__ __forceinline__ void gateN(f2* A, f2 u00, f2 u01, f2 u10, f2 u11) {
    #pragma unroll
    for (int a = 0; a < N; ++a) {
        if (!(a & MASK)) {
            f2 x = A[a], y = A[a | MASK];
            f2 xs = { -x.y, x.x };
            f2 ys = { -y.y, y.x };
            f2 nx = f2s(u00.x) * x;
            nx = __builtin_elementwise_fma(f2s(u00.y), xs, nx);
            nx = __builtin_elementwise_fma(f2s(u01.x), y,  nx);
            nx = __builtin_elementwise_fma(f2s(u01.y), ys, nx);
            f2 ny = f2s(u10.x) * x;
            ny = __builtin_elementwise_fma(f2s(u10.y), xs, ny);
            ny = __builtin_elementwise_fma(f2s(u11.x), y,  ny);
            ny = __builtin_elementwise_fma(f2s(u11.y), ys, ny);
            A[a] = nx; A[a | MASK] = ny;
        }
    }
}
template<int MASK> __device__ __forceinline__ void gate32(f2* A, f2 a, f2 b, f2 c, f2 d) { gateN<MASK,32>(A,a,b,c,d); }
template<int MASK> __device__ __forceinline__ void gate16(f2* A, f2 a, f2 b, f2 c, f2 d) { gateN<MASK,16>(A,a,b,c,d); }

// tail perm on B's register coords (bits = d0, d9, d10, d11, d12)
__device__ __forceinline__ constexpr int permB(int ad) {
    return (ad & 1)
         | ((((ad >> 1) ^ (ad >> 2)) & 1) << 1)
         | ((((ad >> 2) ^ (ad >> 3)) & 1) << 2)
         | ((((ad >> 3) ^ (ad >> 4)) & 1) << 3)
         | ((((ad >> 4) ^  ad      ) & 1) << 4);
}

// Common B-sweep core: 13 gates (arr1/arr2/arr3) + 2 LDS transposes.
// On exit A[] holds arr3 arrangement: d0..4 = t0..4, d5..8 = reg rr,
// d9..11 = t5..7, d12 = h (A[h*16+rr]).
__device__ __forceinline__ void b_gates_core(
    f2* A, f2* S, const f2 (*Ush)[4], int t)
{
    // arr1 gates: d0->q12, d9->q0, d10..12 -> q15,q14,q13
    gate32<1> (A, Ush[0][0],  Ush[0][1],  Ush[0][2],  Ush[0][3]);
    gate32<2> (A, Ush[1][0],  Ush[1][1],  Ush[1][2],  Ush[1][3]);
    gate32<4> (A, Ush[2][0],  Ush[2][1],  Ush[2][2],  Ush[2][3]);
    gate32<8> (A, Ush[3][0],  Ush[3][1],  Ush[3][2],  Ush[3][3]);
    gate32<16>(A, Ush[4][0],  Ush[4][1],  Ush[4][2],  Ush[4][3]);

    // Transpose 1: arr1 {0,9,10,11,12} -> arr2 {1,2,3,4,12}
    #pragma unroll
    for (int h = 0; h < 2; ++h) {
        __syncthreads();
        #pragma unroll
        for (int c = 0; c < 8; ++c) {
            int slot = ((t << 1) | (c << 9)) ^ (((t >> 4) & 7) << 1);
            f2 a0 = A[h*16 + 2*c], a1 = A[h*16 + 2*c + 1];
            *(float4*)&S[slot] = make_float4(a0.x, a0.y, a1.x, a1.y);
        }
        __syncthreads();
        #pragma unroll
        for (int rr = 0; rr < 16; ++rr) {
            int jj = (t & 1) | (rr << 1) | (((t >> 1) & 15) << 5) | (((t >> 5) & 7) << 9);
            A[h*16 + rr] = S[jj ^ (((t >> 1) & 7) << 1)];
        }
    }

    // arr2 gates: d1..4 -> q11,q10,q9,q8
    gate32<1>(A, Ush[5][0], Ush[5][1], Ush[5][2], Ush[5][3]);
    gate32<2>(A, Ush[6][0], Ush[6][1], Ush[6][2], Ush[6][3]);
    gate32<4>(A, Ush[7][0], Ush[7][1], Ush[7][2], Ush[7][3]);
    gate32<8>(A, Ush[8][0], Ush[8][1], Ush[8][2], Ush[8][3]);

    // Transpose 2: arr2 -> arr3 {5,6,7,8,12}
    #pragma unroll
    for (int h = 0; h < 2; ++h) {
        __syncthreads();
        #pragma unroll
        for (int rr = 0; rr < 16; ++rr) {
            int jj = (t & 1) | (rr << 1) | (((t >> 1) & 15) << 5) | (((t >> 5) & 7) << 9);
            S[jj ^ (((t >> 1) & 7) << 1)] = A[h*16 + rr];
        }
        __syncthreads();
        #pragma unroll
        for (int rr = 0; rr < 16; ++rr) {
            int jj = (t & 31) | (rr << 5) | (((t >> 5) & 7) << 9);
            A[h*16 + rr] = S[jj ^ ((rr & 7) << 1)];
        }
    }

    // arr3 gates: d5..8 -> q7,q6,q5,q4
    gate32<1>(A, Ush[9][0],  Ush[9][1],  Ush[9][2],  Ush[9][3]);
    gate32<2>(A, Ush[10][0], Ush[10][1], Ush[10][2], Ush[10][3]);
    gate32<4>(A, Ush[11][0], Ush[11][1], Ush[11][2], Ush[11][3]);
    gate32<8>(A, Ush[12][0], Ush[12][1], Ush[12][2], Ush[12][3]);
}

// arr3 direct store (no perm)
__device__ __forceinline__ void b_store(
    const f2* A, int t, int fixb, f2* base)
{
    #pragma unroll
    for (int h = 0; h < 2; ++h) {
        #pragma unroll
        for (int rr = 0; rr < 16; ++rr) {
            int d = (t & 31) | (rr << 5) | (((t >> 5) & 7) << 9) | (h << 12);
            int m = (d & 511) | (fixb << 9) | (((d >> 9) & 1) << 12) | ((d >> 10) << 13);
            base[m] = A[h*16 + rr];
        }
    }
}

// Sweep 1: fused analytic generation + L1 x13.  No amplitude loads.
// Source s = F^{-1}(g) evaluated via product tree over
// (a0, e1=a1^a2, e2=a2^a3, e3=a3^a4, e4=a4^a0): 61 cmul.
__global__ __launch_bounds__(TPB, 4) void qc_B1_gen(
    const float* __restrict__ x, const float* __restrict__ params,
    f2* __restrict__ st)
{
    __shared__ __align__(16) f2 S[4096];       // 32 KB transpose buffer
    __shared__ f2 Ush[13][4];
    __shared__ f2 V[16][2];

    const int t    = threadIdx.x;
    const int b    = blockIdx.x >> 3;
    const int fixb = blockIdx.x & 7;            // g bits 12..14
    f2* base = st + ((size_t)b << NQ);

    if (t < 16) {                               // qubit t, g bit 15-t
        f2 U[4];
        computeU(params, 0, t, U);
        float s, c;
        sincosf(0.5f * x[b*NQ + t], &s, &c);
        // w = U * (cos h, -i sin h)^T
        V[15 - t][0] = (f2){U[0].x*c + U[1].y*s, U[0].y*c - U[1].x*s};
        V[15 - t][1] = (f2){U[2].x*c + U[3].y*s, U[2].y*c - U[3].x*s};
    } else if (t < 29) {                        // layer-1 gate table
        int tt = t - 16;
        int qb = (tt == 0) ? 12 : (tt == 1) ? 0 : (tt < 5) ? (17 - tt) : (16 - tt);
        computeU(params, 1, qb, Ush[tt]);
    }
    __syncthreads();                             // V + Ush ready

    const int f0 = fixb & 1, f1 = (fixb >> 1) & 1, f2b = (fixb >> 2) & 1;
    const int t0 = t & 1,  t7 = (t >> 7) & 1;

    // pre = prod_{beta=4..13}
    f2 pre = V[4][(t ^ (t >> 1)) & 1];
    #pragma unroll
    for (int bb = 5; bb <= 10; ++bb)
        pre = cmulpk(pre, V[bb][((t >> (bb - 4)) ^ (t >> (bb - 3))) & 1]);
    pre = cmulpk(pre, V[11][t7 ^ f0]);
    pre = cmulpk(pre, V[12][f0 ^ f1]);
    pre = cmulpk(pre, V[13][f1 ^ f2b]);

    f2 P0 = cmulpk(pre, V[3][t0]);               // a0=0
    f2 P1 = cmulpk(pre, V[3][1 ^ t0]);           // a0=1
    f2 Q[4];                                     // Q[a0 + 2*e4] = P[a0]*V[2][e4]
    Q[0] = cmulpk(P0, V[2][0]); Q[1] = cmulpk(P1, V[2][0]);
    Q[2] = cmulpk(P0, V[2][1]); Q[3] = cmulpk(P1, V[2][1]);
    f2 Rr[4];                                    // Rr[e2 + 2*e3] = V[0][e2]*V[1][e3]
    Rr[0] = cmulpk(V[0][0], V[1][0]); Rr[1] = cmulpk(V[0][1], V[1][0]);
    Rr[2] = cmulpk(V[0][0], V[1][1]); Rr[3] = cmulpk(V[0][1], V[1][1]);
    f2 G0 = cmulpk(V[15][0], V[14][f2b]);        // e1=0
    f2 G1 = cmulpk(V[15][1], V[14][1 ^ f2b]);    // e1=1
    f2 TT[8];                                    // TT[e1 + 2*e2 + 4*e3]
    #pragma unroll
    for (int e = 0; e < 4; ++e) {
        TT[2*e]     = cmulpk(G0, Rr[e]);
        TT[2*e + 1] = cmulpk(G1, Rr[e]);
    }

    f2 A[32];
    #pragma unroll
    for (int a = 0; a < 32; ++a) {
        const int a0 = a & 1;
        const int e1 = ((a >> 1) ^ (a >> 2)) & 1;
        const int e2 = ((a >> 2) ^ (a >> 3)) & 1;
        const int e3 = ((a >> 3) ^ (a >> 4)) & 1;
        const int e4 = ((a >> 4) ^  a      ) & 1;
        A[a] = cmulpk(Q[a0 + 2*e4], TT[e1 + 2*e2 + 4*e3]);
    }

    b_gates_core(A, S, Ush, t);
    b_store(A, t, fixb, base);
}

// Sweep 3: tail(lm-1) rename + layer-lm gates on all 13 B-local qubits.
__global__ __launch_bounds__(TPB, 4) void qc_B_heavy(
    const float* __restrict__ params, f2* __restrict__ st, int lm)
{
    __shared__ __align__(16) f2 S[4096];
    __shared__ f2 Ush[13][4];

    const int t    = threadIdx.x;
    const int b    = blockIdx.x >> 3;
    const int fixb = blockIdx.x & 7;            // g bits 12..14
    f2* base = st + ((size_t)b << NQ);

    if (t < 13) {
        int qb = (t == 0) ? 12 : (t == 1) ? 0 : (t < 5) ? (17 - t) : (16 - t);
        computeU(params, lm, qb, Ush[t]);
    }

    f2 R[32];
    #pragma unroll
    for (int k = 0; k < 16; ++k) {
        int j = 2*(t + 256*k);
        int m = (j & 511) | (fixb << 9) | (((j >> 9) & 1) << 12) | ((j >> 10) << 13);
        float4 v = *(const float4*)(base + m);
        R[2*k]   = (f2){v.x, v.y};
        R[2*k+1] = (f2){v.z, v.w};
    }
    f2 A[32];
    #pragma unroll
    for (int a = 0; a < 32; ++a) A[a] = R[permB(a)];
    __syncthreads();                             // Ush ready

    b_gates_core(A, S, Ush, t);
    b_store(A, t, fixb, base);
}

// Sweeps 2,4: [optional pre: layer preL gates q3,q2,q1 on j9..11] + main perm
// + stolen post: layer postL gates q3,q2,q1 on dest bits D9..11 (reg-local).
__global__ __launch_bounds__(TPB, 4) void qc_A_mid(
    const float* __restrict__ params, f2* __restrict__ st, int preL, int postL)
{
    __shared__ __align__(16) f2 S[4096];
    __shared__ f2 Up[3][4], Uq[3][4];
    const int t    = threadIdx.x;
    const int b    = blockIdx.x >> 3;
    const int fix3 = blockIdx.x & 7;
    f2* base = st + ((size_t)b << NQ) + (fix3 << 13);

    if (t < 3 && preL >= 0) computeU(params, preL, 3 - t, Up[t]);  // q3,q2,q1
    if (t >= 4 && t < 7)    computeU(params, postL, 3 - (t - 4), Uq[t - 4]);

    f2 A[32];
    const float4* src = (const float4*)base;
    #pragma unroll
    for (int k = 0; k < 16; ++k) {
        float4 v = src[t + 256*k];
        A[2*k]   = (f2){v.x, v.y};
        A[2*k+1] = (f2){v.z, v.w};
    }
    __syncthreads();                             // U tables ready

    if (preL >= 0) {
        gate32<2>(A, Up[0][0], Up[0][1], Up[0][2], Up[0][3]);   // j9  q3
        gate32<4>(A, Up[1][0], Up[1][1], Up[1][2], Up[1][3]);   // j10 q2
        gate32<8>(A, Up[2][0], Up[2][1], Up[2][2], Up[2][3]);   // j11 q1
    }

    // writeback: stage at arr1 positions, perm-read into dest regs, apply
    // stolen postL gates on D9..11 (Bv bits 1..3), store coalesced.
    float4* dst = (float4*)base;
    #pragma unroll
    for (int h = 0; h < 2; ++h) {
        __syncthreads();
        #pragma unroll
        for (int c = 0; c < 8; ++c) {            // arr1: j = o | (t<<1) | (c<<9), j12=h
            int slot = ((t << 1) | (c << 9)) ^ (((t >> 4) & 7) << 1);
            f2 a0 = A[h*16 + 2*c], a1 = A[h*16 + 2*c + 1];
            *(float4*)&S[slot] = make_float4(a0.x, a0.y, a1.x, a1.y);
        }
        __syncthreads();
        f2 Bv[16];                               // bits: 0 = D0, 1..3 = D9..11
        #pragma unroll
        for (int k = 0; k < 8; ++k) {            // dest d' = 2(t+256k), bit12 = h
            int d  = 2*(t + 256*k);
            int i0 = d ^ (d >> 1) ^ (h << 11);
            int i1 = (d+1) ^ ((d+1) >> 1) ^ (h << 11);
            Bv[2*k]     = S[i0 ^ (((i0 >> 5) & 7) << 1)];
            Bv[2*k + 1] = S[i1 ^ (((i1 >> 5) & 7) << 1)];
        }
        gate16<2>(Bv, Uq[0][0], Uq[0][1], Uq[0][2], Uq[0][3]);  // D9  q3 (postL)
        gate16<4>(Bv, Uq[1][0], Uq[1][1], Uq[1][2], Uq[1][3]);  // D10 q2
        gate16<8>(Bv, Uq[2][0], Uq[2][1], Uq[2][2], Uq[2][3]);  // D11 q1
        #pragma unroll
        for (int k = 0; k < 8; ++k) {
            f2 a0 = Bv[2*k], a1 = Bv[2*k + 1];
            dst[(t + 256*k) | (h << 11)] = make_float4(a0.x, a0.y, a1.x, a1.y);
        }
    }
}

// Sweep 5: tail2 + L3 x13 + chain3-relabel expZ.  Read-only; no state store.
// arr3 amp coords: g0=t6, g1=t7, g2=h, g3..7=t0..4, g8..11=rr, g12..14=fixb,
// g15=t5.  Final f_b = parity(g>>b) (b<=14), f15 = parity(g&0x7FFF).
// Over (rr,h) the 16 sign functionals collapse to 6 buckets:
//   M0 uniform; M1 ±par(rr); M2 ±par(rr>>1); M3 ±par(rr>>2); M4 ±rr3;
//   M5 ±(par(rr)^h); per-thread constant signs fold the t/fixb bits.
__global__ __launch_bounds__(TPB, 4) void qc_B_final(
    const float* __restrict__ params, const f2* __restrict__ st,
    float* __restrict__ out)
{
    __shared__ __align__(16) f2 S[4096];
    __shared__ f2 Ush[13][4];

    const int t    = threadIdx.x;
    const int b    = blockIdx.x >> 3;
    const int fixb = blockIdx.x & 7;
    const f2* base = st + ((size_t)b << NQ);

    if (t < 13) {
        int qb = (t == 0) ? 12 : (t == 1) ? 0 : (t < 5) ? (17 - t) : (16 - t);
        computeU(params, 3, qb, Ush[t]);
    }

    f2 R[32];
    #pragma unroll
    for (int k = 0; k < 16; ++k) {
        int j = 2*(t + 256*k);
        int m = (j & 511) | (fixb << 9) | (((j >> 9) & 1) << 12) | ((j >> 10) << 13);
        float4 v = *(const float4*)(base + m);
        R[2*k]   = (f2){v.x, v.y};
        R[2*k+1] = (f2){v.z, v.w};
    }
    f2 A[32];
    #pragma unroll
    for (int a = 0; a < 32; ++a) A[a] = R[permB(a)];   // tail2 rename
    __syncthreads();

    b_gates_core(A, S, Ush, t);                  // L3 x13; arr3 in registers

    // 6 sign buckets over register slots (h, rr)
    float M0 = 0.f, M1 = 0.f, M2 = 0.f, M3 = 0.f, M4 = 0.f, M5 = 0.f;
    #pragma unroll
    for (int h = 0; h < 2; ++h) {
        #pragma unroll
        for (int rr = 0; rr < 16; ++rr) {
            f2 v = A[h*16 + rr];
            float p = v.x*v.x + v.y*v.y;
            M0 += p;
            M1 += (__popc(rr)      & 1) ? -p : p;
            M2 += (__popc(rr >> 1) & 1) ? -p : p;
            M3 += (__popc(rr >> 2) & 1) ? -p : p;
            M4 += (rr >> 3)             ? -p : p;
            M5 += ((__popc(rr) ^ h) & 1) ? -p : p;
        }
    }

    const int pf   = __popc(fixb) & 1;
    const int t5b  = (t >> 5) & 1, t6b = (t >> 6) & 1, t7b = (t >> 7) & 1;
    const int pt04 = __popc(t & 31) & 1;
    const int bs   = pf ^ t5b;                   // base sign for mid qubits

    float acc[NQ];
    acc[0]  = ((t6b ^ t7b ^ pt04 ^ pf) & 1) ? -M5 : M5;          // q0  (f15)
    acc[1]  = (((fixb >> 2) ^ t5b) & 1)      ? -M0 : M0;          // q1  (f14)
    acc[2]  = ((__popc(fixb >> 1) ^ t5b) & 1)? -M0 : M0;          // q2  (f13)
    acc[3]  = (bs & 1)                        ? -M0 : M0;          // q3  (f12)
    acc[4]  = (bs & 1)                        ? -M4 : M4;          // q4  (f11)
    acc[5]  = (bs & 1)                        ? -M3 : M3;          // q5  (f10)
    acc[6]  = (bs & 1)                        ? -M2 : M2;          // q6  (f9)
    acc[7]  = (bs & 1)                        ? -M1 : M1;          // q7  (f8)
    acc[8]  = ((((t >> 4) & 1) ^ bs) & 1)     ? -M1 : M1;          // q8  (f7)
    acc[9]  = ((__popc((t >> 3) & 3)  ^ bs) & 1) ? -M1 : M1;       // q9  (f6)
    acc[10] = ((__popc((t >> 2) & 7)  ^ bs) & 1) ? -M1 : M1;       // q10 (f5)
    acc[11] = ((__popc((t >> 1) & 15) ^ bs) & 1) ? -M1 : M1;       // q11 (f4)
    acc[12] = ((pt04 ^ bs) & 1)               ? -M1 : M1;          // q12 (f3)
    acc[13] = ((pt04 ^ bs) & 1)               ? -M5 : M5;          // q13 (f2)
    acc[14] = ((t7b ^ pt04 ^ bs) & 1)         ? -M5 : M5;          // q14 (f1)
    acc[15] = ((t6b ^ t7b ^ pt04 ^ bs) & 1)   ? -M5 : M5;          // q15 (f0)

    #pragma unroll
    for (int q = 0; q < NQ; ++q) {
        float v = acc[q];
        v += __shfl_down(v, 32, 64);
        v += __shfl_down(v, 16, 64);
        v += __shfl_down(v,  8, 64);
        v += __shfl_down(v,  4, 64);
        v += __shfl_down(v,  2, 64);
        v += __shfl_down(v,  1, 64);
        acc[q] = v;
    }
    if ((t & 63) == 0) {
        #pragma unroll
        for (int q = 0; q < NQ; ++q)
            atomicAdd(&out[b*NQ + q], acc[q]);
    }
}

extern "C" void kernel_launch(void* const* d_in, const int* in_sizes, int n_in,
                              void* d_out, int out_size, void* d_ws, size_t ws_size,
                              hipStream_t stream)
{
    (void)in_sizes; (void)n_in; (void)ws_size;
    const float* x      = (const float*)d_in[0];   // (512,16) fp32
    const float* params = (const float*)d_in[1];   // (4,16,3) fp32
    float* out = (float*)d_out;                    // (512,16) fp32
    f2* st = (f2*)d_ws;                            // 256 MiB state

    hipMemsetAsync(d_out, 0, (size_t)out_size * sizeof(float), stream);
    qc_B1_gen <<<dim3(512*8), dim3(TPB), 0, stream>>>(x, params, st);
    qc_A_mid  <<<dim3(512*8), dim3(TPB), 0, stream>>>(params, st, 1, 2);
    qc_B_heavy<<<dim3(512*8), dim3(TPB), 0, stream>>>(params, st, 2);
    qc_A_mid  <<<dim3(512*8), dim3(TPB), 0, stream>>>(params, st, -1, 3);
    qc_B_final<<<dim3(512*8), dim3(TPB), 0, stream>>>(params, st, out);
}

// Round 7
// 599.856 us; speedup vs baseline: 1.2555x; 1.2555x over previous
//
#include <hip/hip_runtime.h>

// 16-qubit, depth-4, batch-512 statevector simulator — 6-sweep, packed-FP32.
// (Round-6's 5-sweep merge regressed: folded expZ epilogue via 96 chained
//  shfls cost ~90 us; reverted to round-5 champion, with A_final's identical
//  96-shfl reduction replaced by a 2-stage LDS transpose-reduce.)
//
// State: 512 x 65536 complex64 = 256 MiB in d_ws.
// Reference qubit q <-> flat-index bit beta = 15-q.
// Memory layout per batch: amp with basis index g stored at m = (g>>3) | ((g&7)<<13).
//
// Partition A (blocks fix g bits 0..2): local j = m bits 0..12, j_b = g_{b+3}.
// Partition B (blocks fix g bits 12..14): local d: d0..8 = g3..11, d9 = g15,
//   d10..12 = g0..2.
//
// Chain perm (16 CNOTs), inverse (source s from dest f):
//   s_b = f_b^f_{b+1} (b=0..13), s14 = f14^f15^f0, s15 = f15^f0.
// Split: main (g3..15, A-local) o tail (B-local register rename permB).
// Schedule (6 sweeps):
//   1. qc_B1_gen:   analytic (x)(U_{L0,q} RX(x_q))|0> at full-chain0-permuted
//                   indices (product tree, no loads) + L1 gates on 13 B-qubits.
//   2. qc_A_lite(1): L1 gates q3,q2,q1 + main1 (LDS-staged writeback).
//   3. qc_B_heavy(2): tail1 (reg rename) + L2 x13.
//   4. qc_A_lite(2): L2 q3,q2,q1 + main2.
//   5. qc_B_heavy(3): tail2 + L3 x13.
//   6. qc_A_final:  L3 q3,q2,q1 + expZ (main3.tail3 folded as relabel),
//                   LDS transpose-reduce epilogue (this revision).

#define NQ 16
#define TPB 256

typedef float __attribute__((ext_vector_type(2))) f2;   // (re, im)

__device__ __forceinline__ f2 f2s(float s) { return (f2){s, s}; }

// a (*) b  (complex mul, packed: pk_mul + pk_fma)
__device__ __forceinline__ f2 cmulpk(f2 a, f2 b) {
    f2 bs = { -b.y, b.x };
    f2 r = f2s(a.x) * b;
    return __builtin_elementwise_fma(f2s(a.y), bs, r);
}

// U = RY(t2) * RX(t1) * RZ(t0), row-major [u00,u01,u10,u11]
__device__ __forceinline__ void computeU(const float* params, int layer, int q, f2* U) {
    const float* p = params + (layer*NQ + q)*3;
    float s0, c0, s1, c1, s2, c2;
    sincosf(0.5f*p[0], &s0, &c0);
    sincosf(0.5f*p[1], &s1, &c1);
    sincosf(0.5f*p[2], &s2, &c2);
    f2 m00 = { c1*c0, -c1*s0};
    f2 m01 = { s1*s0, -s1*c0};
    f2 m10 = {-s1*s0, -s1*c0};
    f2 m11 = { c1*c0,  c1*s0};
    U[0] = c2*m00 - s2*m10;
    U[1] = c2*m01 - s2*m11;
    U[2] = s2*m00 + c2*m10;
    U[3] = s2*m01 + c2*m11;
}

// 1q gate on register array A[32], pairing a <-> a|MASK.  8 packed ops/pair.
template<int MASK>
__device__ __forceinline__ void gate32(f2* A, f2 u00, f2 u01, f2 u10, f2 u11) {
    #pragma unroll
    for (int a = 0; a < 32; ++a) {
        if (!(a & MASK)) {
            f2 x = A[a], y = A[a | MASK];
            f2 xs = { -x.y, x.x };
            f2 ys = { -y.y, y.x };
            f2 nx = f2s(u00.x) * x;
            nx = __builtin_elementwise_fma(f2s(u00.y), xs, nx);
            nx = __builtin_elementwise_fma(f2s(u01.x), y,  nx);
            nx = __builtin_elementwise_fma(f2s(u01.y), ys, nx);
            f2 ny = f2s(u10.x) * x;
            ny = __builtin_elementwise_fma(f2s(u10.y), xs, ny);
            ny = __builtin_elementwise_fma(f2s(u11.x), y,  ny);
            ny = __builtin_elementwise_fma(f2s(u11.y), ys, ny);
            A[a] = nx; A[a | MASK] = ny;
        }
    }
}

// tail perm on B's register coords (bits = d0, d9, d10, d11, d12)
__device__ __forceinline__ constexpr int permB(int ad) {
    return (ad & 1)
         | ((((ad >> 1) ^ (ad >> 2)) & 1) << 1)
         | ((((ad >> 2) ^ (ad >> 3)) & 1) << 2)
         | ((((ad >> 3) ^ (ad >> 4)) & 1) << 3)
         | ((((ad >> 4) ^  ad      ) & 1) << 4);
}

// Sweep 1: fused analytic generation + L1 x13.  No amplitude loads.
// Source s = F^{-1}(g) evaluated via product tree over
// (a0, e1=a1^a2, e2=a2^a3, e3=a3^a4, e4=a4^a0): 61 cmul.
__global__ __launch_bounds__(TPB, 4) void qc_B1_gen(
    const float* __restrict__ x, const float* __restrict__ params,
    f2* __restrict__ st)
{
    __shared__ __align__(16) f2 S[4096];       // 32 KB transpose buffer
    __shared__ f2 Ush[13][4];
    __shared__ f2 V[16][2];

    const int t    = threadIdx.x;
    const int b    = blockIdx.x >> 3;
    const int fixb = blockIdx.x & 7;            // g bits 12..14
    f2* base = st + ((size_t)b << NQ);

    if (t < 16) {                               // qubit t, g bit 15-t
        f2 U[4];
        computeU(params, 0, t, U);
        float s, c;
        sincosf(0.5f * x[b*NQ + t], &s, &c);
        // w = U * (cos h, -i sin h)^T
        V[15 - t][0] = (f2){U[0].x*c + U[1].y*s, U[0].y*c - U[1].x*s};
        V[15 - t][1] = (f2){U[2].x*c + U[3].y*s, U[2].y*c - U[3].x*s};
    } else if (t < 29) {                        // layer-1 gate table
        int tt = t - 16;
        int qb = (tt == 0) ? 12 : (tt == 1) ? 0 : (tt < 5) ? (17 - tt) : (16 - tt);
        computeU(params, 1, qb, Ush[tt]);
    }
    __syncthreads();                             // V + Ush ready

    const int f0 = fixb & 1, f1 = (fixb >> 1) & 1, f2b = (fixb >> 2) & 1;
    const int t0 = t & 1,  t7 = (t >> 7) & 1;

    // pre = prod_{beta=4..13}
    f2 pre = V[4][(t ^ (t >> 1)) & 1];
    #pragma unroll
    for (int bb = 5; bb <= 10; ++bb)
        pre = cmulpk(pre, V[bb][((t >> (bb - 4)) ^ (t >> (bb - 3))) & 1]);
    pre = cmulpk(pre, V[11][t7 ^ f0]);
    pre = cmulpk(pre, V[12][f0 ^ f1]);
    pre = cmulpk(pre, V[13][f1 ^ f2b]);

    f2 P0 = cmulpk(pre, V[3][t0]);               // a0=0
    f2 P1 = cmulpk(pre, V[3][1 ^ t0]);           // a0=1
    f2 Q[4];                                     // Q[a0 + 2*e4] = P[a0]*V[2][e4]
    Q[0] = cmulpk(P0, V[2][0]); Q[1] = cmulpk(P1, V[2][0]);
    Q[2] = cmulpk(P0, V[2][1]); Q[3] = cmulpk(P1, V[2][1]);
    f2 Rr[4];                                    // Rr[e2 + 2*e3] = V[0][e2]*V[1][e3]
    Rr[0] = cmulpk(V[0][0], V[1][0]); Rr[1] = cmulpk(V[0][1], V[1][0]);
    Rr[2] = cmulpk(V[0][0], V[1][1]); Rr[3] = cmulpk(V[0][1], V[1][1]);
    f2 G0 = cmulpk(V[15][0], V[14][f2b]);        // e1=0
    f2 G1 = cmulpk(V[15][1], V[14][1 ^ f2b]);    // e1=1
    f2 TT[8];                                    // TT[e1 + 2*e2 + 4*e3]
    #pragma unroll
    for (int e = 0; e < 4; ++e) {
        TT[2*e]     = cmulpk(G0, Rr[e]);
        TT[2*e + 1] = cmulpk(G1, Rr[e]);
    }

    f2 A[32];
    #pragma unroll
    for (int a = 0; a < 32; ++a) {
        const int a0 = a & 1;
        const int e1 = ((a >> 1) ^ (a >> 2)) & 1;
        const int e2 = ((a >> 2) ^ (a >> 3)) & 1;
        const int e3 = ((a >> 3) ^ (a >> 4)) & 1;
        const int e4 = ((a >> 4) ^  a      ) & 1;
        A[a] = cmulpk(Q[a0 + 2*e4], TT[e1 + 2*e2 + 4*e3]);
    }

    // arr1 gates (layer 1): d0->q12, d9->q0, d10..12 -> q15,q14,q13
    gate32<1> (A, Ush[0][0],  Ush[0][1],  Ush[0][2],  Ush[0][3]);
    gate32<2> (A, Ush[1][0],  Ush[1][1],  Ush[1][2],  Ush[1][3]);
    gate32<4> (A, Ush[2][0],  Ush[2][1],  Ush[2][2],  Ush[2][3]);
    gate32<8> (A, Ush[3][0],  Ush[3][1],  Ush[3][2],  Ush[3][3]);
    gate32<16>(A, Ush[4][0],  Ush[4][1],  Ush[4][2],  Ush[4][3]);

    // Transpose 1: arr1 {0,9,10,11,12} -> arr2 {1,2,3,4,12}
    #pragma unroll
    for (int h = 0; h < 2; ++h) {
        __syncthreads();
        #pragma unroll
        for (int c = 0; c < 8; ++c) {
            int slot = ((t << 1) | (c << 9)) ^ (((t >> 4) & 7) << 1);
            f2 a0 = A[h*16 + 2*c], a1 = A[h*16 + 2*c + 1];
            *(float4*)&S[slot] = make_float4(a0.x, a0.y, a1.x, a1.y);
        }
        __syncthreads();
        #pragma unroll
        for (int rr = 0; rr < 16; ++rr) {
            int jj = (t & 1) | (rr << 1) | (((t >> 1) & 15) << 5) | (((t >> 5) & 7) << 9);
            A[h*16 + rr] = S[jj ^ (((t >> 1) & 7) << 1)];
        }
    }

    // arr2 gates: d1..4 -> q11,q10,q9,q8
    gate32<1>(A, Ush[5][0], Ush[5][1], Ush[5][2], Ush[5][3]);
    gate32<2>(A, Ush[6][0], Ush[6][1], Ush[6][2], Ush[6][3]);
    gate32<4>(A, Ush[7][0], Ush[7][1], Ush[7][2], Ush[7][3]);
    gate32<8>(A, Ush[8][0], Ush[8][1], Ush[8][2], Ush[8][3]);

    // Transpose 2: arr2 -> arr3 {5,6,7,8,12}
    #pragma unroll
    for (int h = 0; h < 2; ++h) {
        __syncthreads();
        #pragma unroll
        for (int rr = 0; rr < 16; ++rr) {
            int jj = (t & 1) | (rr << 1) | (((t >> 1) & 15) << 5) | (((t >> 5) & 7) << 9);
            S[jj ^ (((t >> 1) & 7) << 1)] = A[h*16 + rr];
        }
        __syncthreads();
        #pragma unroll
        for (int rr = 0; rr < 16; ++rr) {
            int jj = (t & 31) | (rr << 5) | (((t >> 5) & 7) << 9);
            A[h*16 + rr] = S[jj ^ ((rr & 7) << 1)];
        }
    }

    // arr3 gates: d5..8 -> q7,q6,q5,q4
    gate32<1>(A, Ush[9][0],  Ush[9][1],  Ush[9][2],  Ush[9][3]);
    gate32<2>(A, Ush[10][0], Ush[10][1], Ush[10][2], Ush[10][3]);
    gate32<4>(A, Ush[11][0], Ush[11][1], Ush[11][2], Ush[11][3]);
    gate32<8>(A, Ush[12][0], Ush[12][1], Ush[12][2], Ush[12][3]);

    // direct store from arr3 (no perm)
    #pragma unroll
    for (int h = 0; h < 2; ++h) {
        #pragma unroll
        for (int rr = 0; rr < 16; ++rr) {
            int d = (t & 31) | (rr << 5) | (((t >> 5) & 7) << 9) | (h << 12);
            int m = (d & 511) | (fixb << 9) | (((d >> 9) & 1) << 12) | ((d >> 10) << 13);
            base[m] = A[h*16 + rr];
        }
    }
}

// Sweeps 3,5: tail(lm-1) rename + layer-lm gates on all 13 B-local qubits.
__global__ __launch_bounds__(TPB, 4) void qc_B_heavy(
    const float* __restrict__ params, f2* __restrict__ st, int lm)
{
    __shared__ __align__(16) f2 S[4096];       // 32 KB, one d12 half at a time
    __shared__ f2 Ush[13][4];

    const int t    = threadIdx.x;
    const int b    = blockIdx.x >> 3;
    const int fixb = blockIdx.x & 7;            // g bits 12..14
    f2* base = st + ((size_t)b << NQ);

    // Ush slots: 0:q12(d0) 1:q0(d9) 2:q15(d10) 3:q14(d11) 4:q13(d12)
    //            5..8: q11..q8 (d1..4)   9..12: q7..q4 (d5..8)
    if (t < 13) {
        int qb = (t == 0) ? 12 : (t == 1) ? 0 : (t < 5) ? (17 - t) : (16 - t);
        computeU(params, lm, qb, Ush[t]);
    }

    // load arr1-d: reg a: bit0 = d0, bits1..4 = d9..12; thread bits = d1..8
    f2 R[32];
    #pragma unroll
    for (int k = 0; k < 16; ++k) {
        int j = 2*(t + 256*k);
        int m = (j & 511) | (fixb << 9) | (((j >> 9) & 1) << 12) | ((j >> 10) << 13);
        float4 v = *(const float4*)(base + m);
        R[2*k]   = (f2){v.x, v.y};
        R[2*k+1] = (f2){v.z, v.w};
    }
    // tail perm of layer lm-1: pure compile-time register rename
    f2 A[32];
    #pragma unroll
    for (int a = 0; a < 32; ++a) A[a] = R[permB(a)];
    __syncthreads();                             // Ush ready

    // arr1 gates (layer lm): d0->q12, d9->q0, d10..12 -> q15,q14,q13
    gate32<1> (A, Ush[0][0],  Ush[0][1],  Ush[0][2],  Ush[0][3]);
    gate32<2> (A, Ush[1][0],  Ush[1][1],  Ush[1][2],  Ush[1][3]);
    gate32<4> (A, Ush[2][0],  Ush[2][1],  Ush[2][2],  Ush[2][3]);
    gate32<8> (A, Ush[3][0],  Ush[3][1],  Ush[3][2],  Ush[3][3]);
    gate32<16>(A, Ush[4][0],  Ush[4][1],  Ush[4][2],  Ush[4][3]);

    // Transpose 1: arr1 {0,9,10,11,12} -> arr2 {1,2,3,4,12}
    #pragma unroll
    for (int h = 0; h < 2; ++h) {
        __syncthreads();
        #pragma unroll
        for (int c = 0; c < 8; ++c) {
            int slot = ((t << 1) | (c << 9)) ^ (((t >> 4) & 7) << 1);
            f2 a0 = A[h*16 + 2*c], a1 = A[h*16 + 2*c + 1];
            *(float4*)&S[slot] = make_float4(a0.x, a0.y, a1.x, a1.y);
        }
        __syncthreads();
        #pragma unroll
        for (int rr = 0; rr < 16; ++rr) {
            int jj = (t & 1) | (rr << 1) | (((t >> 1) & 15) << 5) | (((t >> 5) & 7) << 9);
            A[h*16 + rr] = S[jj ^ (((t >> 1) & 7) << 1)];
        }
    }

    // arr2 gates: d1..4 -> q11,q10,q9,q8
    gate32<1>(A, Ush[5][0], Ush[5][1], Ush[5][2], Ush[5][3]);
    gate32<2>(A, Ush[6][0], Ush[6][1], Ush[6][2], Ush[6][3]);
    gate32<4>(A, Ush[7][0], Ush[7][1], Ush[7][2], Ush[7][3]);
    gate32<8>(A, Ush[8][0], Ush[8][1], Ush[8][2], Ush[8][3]);

    // Transpose 2: arr2 -> arr3 {5,6,7,8,12}
    #pragma unroll
    for (int h = 0; h < 2; ++h) {
        __syncthreads();
        #pragma unroll
        for (int rr = 0; rr < 16; ++rr) {
            int jj = (t & 1) | (rr << 1) | (((t >> 1) & 15) << 5) | (((t >> 5) & 7) << 9);
            S[jj ^ (((t >> 1) & 7) << 1)] = A[h*16 + rr];
        }
        __syncthreads();
        #pragma unroll
        for (int rr = 0; rr < 16; ++rr) {
            int jj = (t & 31) | (rr << 5) | (((t >> 5) & 7) << 9);
            A[h*16 + rr] = S[jj ^ ((rr & 7) << 1)];
        }
    }

    // arr3 gates: d5..8 -> q7,q6,q5,q4
    gate32<1>(A, Ush[9][0],  Ush[9][1],  Ush[9][2],  Ush[9][3]);
    gate32<2>(A, Ush[10][0], Ush[10][1], Ush[10][2], Ush[10][3]);
    gate32<4>(A, Ush[11][0], Ush[11][1], Ush[11][2], Ush[11][3]);
    gate32<8>(A, Ush[12][0], Ush[12][1], Ush[12][2], Ush[12][3]);

    // direct store from arr3 (no perm)
    #pragma unroll
    for (int h = 0; h < 2; ++h) {
        #pragma unroll
        for (int rr = 0; rr < 16; ++rr) {
            int d = (t & 31) | (rr << 5) | (((t >> 5) & 7) << 9) | (h << 12);
            int m = (d & 511) | (fixb << 9) | (((d >> 9) & 1) << 12) | ((d >> 10) << 13);
            base[m] = A[h*16 + rr];
        }
    }
}

// Sweeps 2,4: layer-l gates q3,q2,q1 (j9,j10,j11) + main(l) perm in writeback.
__global__ __launch_bounds__(TPB, 4) void qc_A_lite(
    const float* __restrict__ params, f2* __restrict__ st, int layer)
{
    __shared__ __align__(16) f2 S[4096];
    __shared__ f2 Ush[3][4];
    const int t    = threadIdx.x;
    const int b    = blockIdx.x >> 3;
    const int fix3 = blockIdx.x & 7;
    f2* base = st + ((size_t)b << NQ) + (fix3 << 13);

    if (t < 3) computeU(params, layer, 3 - t, Ush[t]);   // Ush[0]=q3 Ush[1]=q2 Ush[2]=q1

    f2 A[32];
    const float4* src = (const float4*)base;
    #pragma unroll
    for (int k = 0; k < 16; ++k) {
        float4 v = src[t + 256*k];
        A[2*k]   = (f2){v.x, v.y};
        A[2*k+1] = (f2){v.z, v.w};
    }
    __syncthreads();                             // Ush ready

    gate32<2>(A, Ush[0][0], Ush[0][1], Ush[0][2], Ush[0][3]);   // j9  q3
    gate32<4>(A, Ush[1][0], Ush[1][1], Ush[1][2], Ush[1][3]);   // j10 q2
    gate32<8>(A, Ush[2][0], Ush[2][1], Ush[2][2], Ush[2][3]);   // j11 q1

    // writeback: stage at arr1 positions, read with main-chain perm, store coalesced
    float4* dst = (float4*)base;
    #pragma unroll
    for (int h = 0; h < 2; ++h) {
        __syncthreads();
        #pragma unroll
        for (int c = 0; c < 8; ++c) {            // arr1: j = o | (t<<1) | (c<<9), j12=h
            int slot = ((t << 1) | (c << 9)) ^ (((t >> 4) & 7) << 1);
            f2 a0 = A[h*16 + 2*c], a1 = A[h*16 + 2*c + 1];
            *(float4*)&S[slot] = make_float4(a0.x, a0.y, a1.x, a1.y);
        }
        __syncthreads();
        #pragma unroll
        for (int k = 0; k < 8; ++k) {            // dest d' = 2(t+256k), bit12 = h
            int d  = 2*(t + 256*k);
            int i0 = d ^ (d >> 1) ^ (h << 11);
            int i1 = (d+1) ^ ((d+1) >> 1) ^ (h << 11);
            f2 a0 = S[i0 ^ (((i0 >> 5) & 7) << 1)];
            f2 a1 = S[i1 ^ (((i1 >> 5) & 7) << 1)];
            dst[(t + 256*k) | (h << 11)] = make_float4(a0.x, a0.y, a1.x, a1.y);
        }
    }
}

// Sweep 6: L3 gates q3,q2,q1, then expZ with main3.tail3 folded as relabel.
// u bits: 0..2 = fix3, 3 = a0, 4..11 = t, 12..15 = a1..a4.
// f_b = parity(u>>b) (b<=14), f15 = parity(u & 0x7FFF).
// Epilogue: 2-stage LDS transpose-reduce (36 shallow DS ops, was 96 chained shfl).
__global__ __launch_bounds__(TPB) void qc_A_final(
    const float* __restrict__ params, const f2* __restrict__ st,
    float* __restrict__ out)
{
    __shared__ f2 Ush[3][4];
    __shared__ float F[16*272];                  // stride 272 (= 16 mod 32): reads <=2-way
    const int t    = threadIdx.x;
    const int b    = blockIdx.x >> 3;
    const int fix3 = blockIdx.x & 7;
    const f2* base = st + ((size_t)b << NQ) + (fix3 << 13);

    if (t < 3) computeU(params, 3, 3 - t, Ush[t]);

    f2 A[32];
    const float4* src = (const float4*)base;
    #pragma unroll
    for (int k = 0; k < 16; ++k) {
        float4 v = src[t + 256*k];
        A[2*k]   = (f2){v.x, v.y};
        A[2*k+1] = (f2){v.z, v.w};
    }
    __syncthreads();

    gate32<2>(A, Ush[0][0], Ush[0][1], Ush[0][2], Ush[0][3]);   // j9  q3
    gate32<4>(A, Ush[1][0], Ush[1][1], Ush[1][2], Ush[1][3]);   // j10 q2
    gate32<8>(A, Ush[2][0], Ush[2][1], Ush[2][2], Ush[2][3]);   // j11 q1

    // 5 register-parity sign buckets:
    // M1 = par(a1..a4) -> q3..q11 ; M2 = par(a0..a4) -> q12..q15
    // M3 = par(a2..a4) -> q2 ; M4 = par(a3,a4) -> q1 ; M5 = par(a0..a3) -> q0
    float m1 = 0.f, m2 = 0.f, m3 = 0.f, m4 = 0.f, m5 = 0.f;
    #pragma unroll
    for (int a = 0; a < 32; ++a) {
        float p = A[a].x*A[a].x + A[a].y*A[a].y;
        m1 += (__popc(a & 0x1E) & 1) ? -p : p;
        m2 += (__popc(a & 0x1F) & 1) ? -p : p;
        m3 += (__popc(a & 0x1C) & 1) ? -p : p;
        m4 += (__popc(a & 0x18) & 1) ? -p : p;
        m5 += (__popc(a & 0x0F) & 1) ? -p : p;
    }
    const int pt = __popc(t) & 1;
    const int pf = __popc(fix3) & 1;
    float acc[NQ];
    acc[0] = ((pt ^ pf) & 1) ? -m5 : m5;         // f15
    acc[1] = m4;                                  // f14
    acc[2] = m3;                                  // f13
    acc[3] = m1;                                  // f12
    #pragma unroll
    for (int q = 4; q <= 11; ++q) {               // f_{15-q}: t-part = par(t >> (11-q))
        int s = __popc(t >> (11 - q)) & 1;
        acc[q] = s ? -m1 : m1;
    }
    acc[12] = pt ? -m2 : m2;
    acc[13] = ((pt ^ (fix3 >> 2)) & 1) ? -m2 : m2;
    acc[14] = ((pt ^ __popc(fix3 >> 1)) & 1) ? -m2 : m2;
    acc[15] = ((pt ^ pf) & 1) ? -m2 : m2;

    // Stage 1: scatter signed values to LDS, one row per qubit.
    #pragma unroll
    for (int q = 0; q < NQ; ++q) F[q*272 + t] = acc[q];
    __syncthreads();
    // Stage 2: thread t reduces qubit t>>4, chunk t&15 (16 reads, <=2-way banks),
    // then 4-level shfl within 16-lane groups; 16 atomics per block.
    const int qq = t >> 4, ii = t & 15;
    float s = 0.f;
    #pragma unroll
    for (int c = 0; c < 16; ++c) s += F[qq*272 + ii + 16*c];
    s += __shfl_down(s, 8, 16);
    s += __shfl_down(s, 4, 16);
    s += __shfl_down(s, 2, 16);
    s += __shfl_down(s, 1, 16);
    if (ii == 0) atomicAdd(&out[b*NQ + qq], s);
}

extern "C" void kernel_launch(void* const* d_in, const int* in_sizes, int n_in,
                              void* d_out, int out_size, void* d_ws, size_t ws_size,
                              hipStream_t stream)
{
    (void)in_sizes; (void)n_in; (void)ws_size;
    const float* x      = (const float*)d_in[0];   // (512,16) fp32
    const float* params = (const float*)d_in[1];   // (4,16,3) fp32
    float* out = (float*)d_out;                    // (512,16) fp32
    f2* st = (f2*)d_ws;                            // 256 MiB state

    hipMemsetAsync(d_out, 0, (size_t)out_size * sizeof(float), stream);
    qc_B1_gen <<<dim3(512*8), dim3(TPB), 0, stream>>>(x, params, st);
    qc_A_lite <<<dim3(512*8), dim3(TPB), 0, stream>>>(params, st, 1);
    qc_B_heavy<<<dim3(512*8), dim3(TPB), 0, stream>>>(params, st, 2);
    qc_A_lite <<<dim3(512*8), dim3(TPB), 0, stream>>>(params, st, 2);
    qc_B_heavy<<<dim3(512*8), dim3(TPB), 0, stream>>>(params, st, 3);
    qc_A_final<<<dim3(512*8), dim3(TPB), 0, stream>>>(params, st, out);
}

// Round 8
// 555.072 us; speedup vs baseline: 1.3567x; 1.0807x over previous
//
#include <hip/hip_runtime.h>

// 16-qubit, depth-4, batch-512 statevector simulator — 6-sweep, packed-FP32,
// gate-rebalanced: B sweeps do 11 gates (was 13); A sweeps do 5 (was 3).
// q12 (g3=j0) and q0 (g15=j12) are register-local in A's natural layout and
// commute past main(l) (applied pre-perm) and tail(l) (next kernel's load),
// so they move from the VALU-tight B sweeps to the memory-bound A sweeps.
//
// State: 512 x 65536 complex64 = 256 MiB in d_ws.
// Reference qubit q <-> flat-index bit beta = 15-q.
// Memory layout per batch: amp with basis index g stored at m = (g>>3) | ((g&7)<<13).
//
// Partition A (blocks fix g bits 0..2): local j = m bits 0..12, j_b = g_{b+3}.
// Partition B (blocks fix g bits 12..14): local d: d0..8 = g3..11, d9 = g15,
//   d10..12 = g0..2.
//
// Chain perm (16 CNOTs), inverse (source s from dest f):
//   s_b = f_b^f_{b+1} (b=0..13), s14 = f14^f15^f0, s15 = f15^f0.
// Split: main (g3..15, A-local) o tail (B-local register rename permB).
// Schedule (6 sweeps):
//   1. qc_B1_gen:   analytic (x)(U_{L0,q} RX(x_q))|0> at full-chain0-permuted
//                   indices (product tree, no loads) + L1 x11 (B-local).
//   2. qc_A_lite(1): L1 {q12,q3,q2,q1,q0} + main1 (LDS-staged writeback).
//   3. qc_B_heavy(2): tail1 (reg rename) + L2 x11.
//   4. qc_A_lite(2): L2 x5 + main2.
//   5. qc_B_heavy(3): tail2 + L3 x11.
//   6. qc_A_final:  L3 x5 + expZ (main3.tail3 folded as relabel),
//                   LDS transpose-reduce epilogue.

#define NQ 16
#define TPB 256

typedef float __attribute__((ext_vector_type(2))) f2;   // (re, im)

__device__ __forceinline__ f2 f2s(float s) { return (f2){s, s}; }

// a (*) b  (complex mul, packed: pk_mul + pk_fma)
__device__ __forceinline__ f2 cmulpk(f2 a, f2 b) {
    f2 bs = { -b.y, b.x };
    f2 r = f2s(a.x) * b;
    return __builtin_elementwise_fma(f2s(a.y), bs, r);
}

// U = RY(t2) * RX(t1) * RZ(t0), row-major [u00,u01,u10,u11]
__device__ __forceinline__ void computeU(const float* params, int layer, int q, f2* U) {
    const float* p = params + (layer*NQ + q)*3;
    float s0, c0, s1, c1, s2, c2;
    sincosf(0.5f*p[0], &s0, &c0);
    sincosf(0.5f*p[1], &s1, &c1);
    sincosf(0.5f*p[2], &s2, &c2);
    f2 m00 = { c1*c0, -c1*s0};
    f2 m01 = { s1*s0, -s1*c0};
    f2 m10 = {-s1*s0, -s1*c0};
    f2 m11 = { c1*c0,  c1*s0};
    U[0] = c2*m00 - s2*m10;
    U[1] = c2*m01 - s2*m11;
    U[2] = s2*m00 + c2*m10;
    U[3] = s2*m01 + c2*m11;
}

// 1q gate on register array A[32], pairing a <-> a|MASK.  8 packed ops/pair.
template<int MASK>
__device__ __forceinline__ void gate32(f2* A, f2 u00, f2 u01, f2 u10, f2 u11) {
    #pragma unroll
    for (int a = 0; a < 32; ++a) {
        if (!(a & MASK)) {
            f2 x = A[a], y = A[a | MASK];
            f2 xs = { -x.y, x.x };
            f2 ys = { -y.y, y.x };
            f2 nx = f2s(u00.x) * x;
            nx = __builtin_elementwise_fma(f2s(u00.y), xs, nx);
            nx = __builtin_elementwise_fma(f2s(u01.x), y,  nx);
            nx = __builtin_elementwise_fma(f2s(u01.y), ys, nx);
            f2 ny = f2s(u10.x) * x;
            ny = __builtin_elementwise_fma(f2s(u10.y), xs, ny);
            ny = __builtin_elementwise_fma(f2s(u11.x), y,  ny);
            ny = __builtin_elementwise_fma(f2s(u11.y), ys, ny);
            A[a] = nx; A[a | MASK] = ny;
        }
    }
}

// tail perm on B's register coords (bits = d0, d9, d10, d11, d12)
__device__ __forceinline__ constexpr int permB(int ad) {
    return (ad & 1)
         | ((((ad >> 1) ^ (ad >> 2)) & 1) << 1)
         | ((((ad >> 2) ^ (ad >> 3)) & 1) << 2)
         | ((((ad >> 3) ^ (ad >> 4)) & 1) << 3)
         | ((((ad >> 4) ^  ad      ) & 1) << 4);
}

// B-sweep Ush table (11 entries): 0:q15(d10) 1:q14(d11) 2:q13(d12)
//   3..6: q11..q8 (d1..4)   7..10: q7..q4 (d5..8)
__device__ __forceinline__ int b_qb(int tt) { return (tt < 3) ? (15 - tt) : (14 - tt); }

// Sweep 1: fused analytic generation + L1 x11.  No amplitude loads.
// Source s = F^{-1}(g) evaluated via product tree over
// (a0, e1=a1^a2, e2=a2^a3, e3=a3^a4, e4=a4^a0): 61 cmul.
__global__ __launch_bounds__(TPB, 4) void qc_B1_gen(
    const float* __restrict__ x, const float* __restrict__ params,
    f2* __restrict__ st)
{
    __shared__ __align__(16) f2 S[4096];       // 32 KB transpose buffer
    __shared__ f2 Ush[11][4];
    __shared__ f2 V[16][2];

    const int t    = threadIdx.x;
    const int b    = blockIdx.x >> 3;
    const int fixb = blockIdx.x & 7;            // g bits 12..14
    f2* base = st + ((size_t)b << NQ);

    if (t < 16) {                               // qubit t, g bit 15-t
        f2 U[4];
        computeU(params, 0, t, U);
        float s, c;
        sincosf(0.5f * x[b*NQ + t], &s, &c);
        // w = U * (cos h, -i sin h)^T
        V[15 - t][0] = (f2){U[0].x*c + U[1].y*s, U[0].y*c - U[1].x*s};
        V[15 - t][1] = (f2){U[2].x*c + U[3].y*s, U[2].y*c - U[3].x*s};
    } else if (t < 27) {                        // layer-1 gate table (11)
        int tt = t - 16;
        computeU(params, 1, b_qb(tt), Ush[tt]);
    }
    __syncthreads();                             // V + Ush ready

    const int f0 = fixb & 1, f1 = (fixb >> 1) & 1, f2b = (fixb >> 2) & 1;
    const int t0 = t & 1,  t7 = (t >> 7) & 1;

    // pre = prod_{beta=4..13}
    f2 pre = V[4][(t ^ (t >> 1)) & 1];
    #pragma unroll
    for (int bb = 5; bb <= 10; ++bb)
        pre = cmulpk(pre, V[bb][((t >> (bb - 4)) ^ (t >> (bb - 3))) & 1]);
    pre = cmulpk(pre, V[11][t7 ^ f0]);
    pre = cmulpk(pre, V[12][f0 ^ f1]);
    pre = cmulpk(pre, V[13][f1 ^ f2b]);

    f2 P0 = cmulpk(pre, V[3][t0]);               // a0=0
    f2 P1 = cmulpk(pre, V[3][1 ^ t0]);           // a0=1
    f2 Q[4];                                     // Q[a0 + 2*e4] = P[a0]*V[2][e4]
    Q[0] = cmulpk(P0, V[2][0]); Q[1] = cmulpk(P1, V[2][0]);
    Q[2] = cmulpk(P0, V[2][1]); Q[3] = cmulpk(P1, V[2][1]);
    f2 Rr[4];                                    // Rr[e2 + 2*e3] = V[0][e2]*V[1][e3]
    Rr[0] = cmulpk(V[0][0], V[1][0]); Rr[1] = cmulpk(V[0][1], V[1][0]);
    Rr[2] = cmulpk(V[0][0], V[1][1]); Rr[3] = cmulpk(V[0][1], V[1][1]);
    f2 G0 = cmulpk(V[15][0], V[14][f2b]);        // e1=0
    f2 G1 = cmulpk(V[15][1], V[14][1 ^ f2b]);    // e1=1
    f2 TT[8];                                    // TT[e1 + 2*e2 + 4*e3]
    #pragma unroll
    for (int e = 0; e < 4; ++e) {
        TT[2*e]     = cmulpk(G0, Rr[e]);
        TT[2*e + 1] = cmulpk(G1, Rr[e]);
    }

    f2 A[32];
    #pragma unroll
    for (int a = 0; a < 32; ++a) {
        const int a0 = a & 1;
        const int e1 = ((a >> 1) ^ (a >> 2)) & 1;
        const int e2 = ((a >> 2) ^ (a >> 3)) & 1;
        const int e3 = ((a >> 3) ^ (a >> 4)) & 1;
        const int e4 = ((a >> 4) ^  a      ) & 1;
        A[a] = cmulpk(Q[a0 + 2*e4], TT[e1 + 2*e2 + 4*e3]);
    }

    // arr1 gates (layer 1): d10..12 -> q15,q14,q13 (q12/q0 moved to A sweep)
    gate32<4> (A, Ush[0][0], Ush[0][1], Ush[0][2], Ush[0][3]);
    gate32<8> (A, Ush[1][0], Ush[1][1], Ush[1][2], Ush[1][3]);
    gate32<16>(A, Ush[2][0], Ush[2][1], Ush[2][2], Ush[2][3]);

    // Transpose 1: arr1 {0,9,10,11,12} -> arr2 {1,2,3,4,12}
    #pragma unroll
    for (int h = 0; h < 2; ++h) {
        __syncthreads();
        #pragma unroll
        for (int c = 0; c < 8; ++c) {
            int slot = ((t << 1) | (c << 9)) ^ (((t >> 4) & 7) << 1);
            f2 a0 = A[h*16 + 2*c], a1 = A[h*16 + 2*c + 1];
            *(float4*)&S[slot] = make_float4(a0.x, a0.y, a1.x, a1.y);
        }
        __syncthreads();
        #pragma unroll
        for (int rr = 0; rr < 16; ++rr) {
            int jj = (t & 1) | (rr << 1) | (((t >> 1) & 15) << 5) | (((t >> 5) & 7) << 9);
            A[h*16 + rr] = S[jj ^ (((t >> 1) & 7) << 1)];
        }
    }

    // arr2 gates: d1..4 -> q11,q10,q9,q8
    gate32<1>(A, Ush[3][0], Ush[3][1], Ush[3][2], Ush[3][3]);
    gate32<2>(A, Ush[4][0], Ush[4][1], Ush[4][2], Ush[4][3]);
    gate32<4>(A, Ush[5][0], Ush[5][1], Ush[5][2], Ush[5][3]);
    gate32<8>(A, Ush[6][0], Ush[6][1], Ush[6][2], Ush[6][3]);

    // Transpose 2: arr2 -> arr3 {5,6,7,8,12}
    #pragma unroll
    for (int h = 0; h < 2; ++h) {
        __syncthreads();
        #pragma unroll
        for (int rr = 0; rr < 16; ++rr) {
            int jj = (t & 1) | (rr << 1) | (((t >> 1) & 15) << 5) | (((t >> 5) & 7) << 9);
            S[jj ^ (((t >> 1) & 7) << 1)] = A[h*16 + rr];
        }
        __syncthreads();
        #pragma unroll
        for (int rr = 0; rr < 16; ++rr) {
            int jj = (t & 31) | (rr << 5) | (((t >> 5) & 7) << 9);
            A[h*16 + rr] = S[jj ^ ((rr & 7) << 1)];
        }
    }

    // arr3 gates: d5..8 -> q7,q6,q5,q4
    gate32<1>(A, Ush[7][0],  Ush[7][1],  Ush[7][2],  Ush[7][3]);
    gate32<2>(A, Ush[8][0],  Ush[8][1],  Ush[8][2],  Ush[8][3]);
    gate32<4>(A, Ush[9][0],  Ush[9][1],  Ush[9][2],  Ush[9][3]);
    gate32<8>(A, Ush[10][0], Ush[10][1], Ush[10][2], Ush[10][3]);

    // direct store from arr3 (no perm)
    #pragma unroll
    for (int h = 0; h < 2; ++h) {
        #pragma unroll
        for (int rr = 0; rr < 16; ++rr) {
            int d = (t & 31) | (rr << 5) | (((t >> 5) & 7) << 9) | (h << 12);
            int m = (d & 511) | (fixb << 9) | (((d >> 9) & 1) << 12) | ((d >> 10) << 13);
            base[m] = A[h*16 + rr];
        }
    }
}

// Sweeps 3,5: tail(lm-1) rename + layer-lm gates on 11 B-local qubits.
__global__ __launch_bounds__(TPB, 4) void qc_B_heavy(
    const float* __restrict__ params, f2* __restrict__ st, int lm)
{
    __shared__ __align__(16) f2 S[4096];       // 32 KB, one d12 half at a time
    __shared__ f2 Ush[11][4];

    const int t    = threadIdx.x;
    const int b    = blockIdx.x >> 3;
    const int fixb = blockIdx.x & 7;            // g bits 12..14
    f2* base = st + ((size_t)b << NQ);

    if (t < 11) computeU(params, lm, b_qb(t), Ush[t]);

    // load arr1-d: reg a: bit0 = d0, bits1..4 = d9..12; thread bits = d1..8
    f2 R[32];
    #pragma unroll
    for (int k = 0; k < 16; ++k) {
        int j = 2*(t + 256*k);
        int m = (j & 511) | (fixb << 9) | (((j >> 9) & 1) << 12) | ((j >> 10) << 13);
        float4 v = *(const float4*)(base + m);
        R[2*k]   = (f2){v.x, v.y};
        R[2*k+1] = (f2){v.z, v.w};
    }
    // tail perm of layer lm-1: pure compile-time register rename
    f2 A[32];
    #pragma unroll
    for (int a = 0; a < 32; ++a) A[a] = R[permB(a)];
    __syncthreads();                             // Ush ready

    // arr1 gates (layer lm): d10..12 -> q15,q14,q13
    gate32<4> (A, Ush[0][0], Ush[0][1], Ush[0][2], Ush[0][3]);
    gate32<8> (A, Ush[1][0], Ush[1][1], Ush[1][2], Ush[1][3]);
    gate32<16>(A, Ush[2][0], Ush[2][1], Ush[2][2], Ush[2][3]);

    // Transpose 1: arr1 {0,9,10,11,12} -> arr2 {1,2,3,4,12}
    #pragma unroll
    for (int h = 0; h < 2; ++h) {
        __syncthreads();
        #pragma unroll
        for (int c = 0; c < 8; ++c) {
            int slot = ((t << 1) | (c << 9)) ^ (((t >> 4) & 7) << 1);
            f2 a0 = A[h*16 + 2*c], a1 = A[h*16 + 2*c + 1];
            *(float4*)&S[slot] = make_float4(a0.x, a0.y, a1.x, a1.y);
        }
        __syncthreads();
        #pragma unroll
        for (int rr = 0; rr < 16; ++rr) {
            int jj = (t & 1) | (rr << 1) | (((t >> 1) & 15) << 5) | (((t >> 5) & 7) << 9);
            A[h*16 + rr] = S[jj ^ (((t >> 1) & 7) << 1)];
        }
    }

    // arr2 gates: d1..4 -> q11,q10,q9,q8
    gate32<1>(A, Ush[3][0], Ush[3][1], Ush[3][2], Ush[3][3]);
    gate32<2>(A, Ush[4][0], Ush[4][1], Ush[4][2], Ush[4][3]);
    gate32<4>(A, Ush[5][0], Ush[5][1], Ush[5][2], Ush[5][3]);
    gate32<8>(A, Ush[6][0], Ush[6][1], Ush[6][2], Ush[6][3]);

    // Transpose 2: arr2 -> arr3 {5,6,7,8,12}
    #pragma unroll
    for (int h = 0; h < 2; ++h) {
        __syncthreads();
        #pragma unroll
        for (int rr = 0; rr < 16; ++rr) {
            int jj = (t & 1) | (rr << 1) | (((t >> 1) & 15) << 5) | (((t >> 5) & 7) << 9);
            S[jj ^ (((t >> 1) & 7) << 1)] = A[h*16 + rr];
        }
        __syncthreads();
        #pragma unroll
        for (int rr = 0; rr < 16; ++rr) {
            int jj = (t & 31) | (rr << 5) | (((t >> 5) & 7) << 9);
            A[h*16 + rr] = S[jj ^ ((rr & 7) << 1)];
        }
    }

    // arr3 gates: d5..8 -> q7,q6,q5,q4
    gate32<1>(A, Ush[7][0],  Ush[7][1],  Ush[7][2],  Ush[7][3]);
    gate32<2>(A, Ush[8][0],  Ush[8][1],  Ush[8][2],  Ush[8][3]);
    gate32<4>(A, Ush[9][0],  Ush[9][1],  Ush[9][2],  Ush[9][3]);
    gate32<8>(A, Ush[10][0], Ush[10][1], Ush[10][2], Ush[10][3]);

    // direct store from arr3 (no perm)
    #pragma unroll
    for (int h = 0; h < 2; ++h) {
        #pragma unroll
        for (int rr = 0; rr < 16; ++rr) {
            int d = (t & 31) | (rr << 5) | (((t >> 5) & 7) << 9) | (h << 12);
            int m = (d & 511) | (fixb << 9) | (((d >> 9) & 1) << 12) | ((d >> 10) << 13);
            base[m] = A[h*16 + rr];
        }
    }
}

// Sweeps 2,4: layer-l gates {q12,q3,q2,q1,q0} (reg bits j0,j9..12) + main(l).
__global__ __launch_bounds__(TPB, 4) void qc_A_lite(
    const float* __restrict__ params, f2* __restrict__ st, int layer)
{
    __shared__ __align__(16) f2 S[4096];
    __shared__ f2 Ush[5][4];
    const int t    = threadIdx.x;
    const int b    = blockIdx.x >> 3;
    const int fix3 = blockIdx.x & 7;
    f2* base = st + ((size_t)b << NQ) + (fix3 << 13);

    // Ush by mask: 0:q12(j0) 1:q3(j9) 2:q2(j10) 3:q1(j11) 4:q0(j12)
    if (t < 5) computeU(params, layer, (t == 0) ? 12 : 4 - t, Ush[t]);

    f2 A[32];
    const float4* src = (const float4*)base;
    #pragma unroll
    for (int k = 0; k < 16; ++k) {
        float4 v = src[t + 256*k];
        A[2*k]   = (f2){v.x, v.y};
        A[2*k+1] = (f2){v.z, v.w};
    }
    __syncthreads();                             // Ush ready

    gate32<1> (A, Ush[0][0], Ush[0][1], Ush[0][2], Ush[0][3]);  // j0  q12
    gate32<2> (A, Ush[1][0], Ush[1][1], Ush[1][2], Ush[1][3]);  // j9  q3
    gate32<4> (A, Ush[2][0], Ush[2][1], Ush[2][2], Ush[2][3]);  // j10 q2
    gate32<8> (A, Ush[3][0], Ush[3][1], Ush[3][2], Ush[3][3]);  // j11 q1
    gate32<16>(A, Ush[4][0], Ush[4][1], Ush[4][2], Ush[4][3]);  // j12 q0

    // writeback: stage at arr1 positions, read with main-chain perm, store coalesced
    float4* dst = (float4*)base;
    #pragma unroll
    for (int h = 0; h < 2; ++h) {
        __syncthreads();
        #pragma unroll
        for (int c = 0; c < 8; ++c) {            // arr1: j = o | (t<<1) | (c<<9), j12=h
            int slot = ((t << 1) | (c << 9)) ^ (((t >> 4) & 7) << 1);
            f2 a0 = A[h*16 + 2*c], a1 = A[h*16 + 2*c + 1];
            *(float4*)&S[slot] = make_float4(a0.x, a0.y, a1.x, a1.y);
        }
        __syncthreads();
        #pragma unroll
        for (int k = 0; k < 8; ++k) {            // dest d' = 2(t+256k), bit12 = h
            int d  = 2*(t + 256*k);
            int i0 = d ^ (d >> 1) ^ (h << 11);
            int i1 = (d+1) ^ ((d+1) >> 1) ^ (h << 11);
            f2 a0 = S[i0 ^ (((i0 >> 5) & 7) << 1)];
            f2 a1 = S[i1 ^ (((i1 >> 5) & 7) << 1)];
            dst[(t + 256*k) | (h << 11)] = make_float4(a0.x, a0.y, a1.x, a1.y);
        }
    }
}

// Sweep 6: L3 gates {q12,q3,q2,q1,q0}, then expZ with main3.tail3 folded.
// u bits: 0..2 = fix3, 3 = a0, 4..11 = t, 12..15 = a1..a4.
// f_b = parity(u>>b) (b<=14), f15 = parity(u & 0x7FFF).
__global__ __launch_bounds__(TPB) void qc_A_final(
    const float* __restrict__ params, const f2* __restrict__ st,
    float* __restrict__ out)
{
    __shared__ f2 Ush[5][4];
    __shared__ float F[16*272];                  // stride 272: reads <=2-way banks
    const int t    = threadIdx.x;
    const int b    = blockIdx.x >> 3;
    const int fix3 = blockIdx.x & 7;
    const f2* base = st + ((size_t)b << NQ) + (fix3 << 13);

    if (t < 5) computeU(params, 3, (t == 0) ? 12 : 4 - t, Ush[t]);

    f2 A[32];
    const float4* src = (const float4*)base;
    #pragma unroll
    for (int k = 0; k < 16; ++k) {
        float4 v = src[t + 256*k];
        A[2*k]   = (f2){v.x, v.y};
        A[2*k+1] = (f2){v.z, v.w};
    }
    __syncthreads();

    gate32<1> (A, Ush[0][0], Ush[0][1], Ush[0][2], Ush[0][3]);  // j0  q12
    gate32<2> (A, Ush[1][0], Ush[1][1], Ush[1][2], Ush[1][3]);  // j9  q3
    gate32<4> (A, Ush[2][0], Ush[2][1], Ush[2][2], Ush[2][3]);  // j10 q2
    gate32<8> (A, Ush[3][0], Ush[3][1], Ush[3][2], Ush[3][3]);  // j11 q1
    gate32<16>(A, Ush[4][0], Ush[4][1], Ush[4][2], Ush[4][3]);  // j12 q0

    // 5 register-parity sign buckets:
    // M1 = par(a1..a4) -> q3..q11 ; M2 = par(a0..a4) -> q12..q15
    // M3 = par(a2..a4) -> q2 ; M4 = par(a3,a4) -> q1 ; M5 = par(a0..a3) -> q0
    float m1 = 0.f, m2 = 0.f, m3 = 0.f, m4 = 0.f, m5 = 0.f;
    #pragma unroll
    for (int a = 0; a < 32; ++a) {
        float p = A[a].x*A[a].x + A[a].y*A[a].y;
        m1 += (__popc(a & 0x1E) & 1) ? -p : p;
        m2 += (__popc(a & 0x1F) & 1) ? -p : p;
        m3 += (__popc(a & 0x1C) & 1) ? -p : p;
        m4 += (__popc(a & 0x18) & 1) ? -p : p;
        m5 += (__popc(a & 0x0F) & 1) ? -p : p;
    }
    const int pt = __popc(t) & 1;
    const int pf = __popc(fix3) & 1;
    float acc[NQ];
    acc[0] = ((pt ^ pf) & 1) ? -m5 : m5;         // f15
    acc[1] = m4;                                  // f14
    acc[2] = m3;                                  // f13
    acc[3] = m1;                                  // f12
    #pragma unroll
    for (int q = 4; q <= 11; ++q) {               // f_{15-q}: t-part = par(t >> (11-q))
        int s = __popc(t >> (11 - q)) & 1;
        acc[q] = s ? -m1 : m1;
    }
    acc[12] = pt ? -m2 : m2;
    acc[13] = ((pt ^ (fix3 >> 2)) & 1) ? -m2 : m2;
    acc[14] = ((pt ^ __popc(fix3 >> 1)) & 1) ? -m2 : m2;
    acc[15] = ((pt ^ pf) & 1) ? -m2 : m2;

    // Stage 1: scatter signed values to LDS, one row per qubit.
    #pragma unroll
    for (int q = 0; q < NQ; ++q) F[q*272 + t] = acc[q];
    __syncthreads();
    // Stage 2: thread t reduces qubit t>>4, chunk t&15, then 4-level shfl.
    const int qq = t >> 4, ii = t & 15;
    float s = 0.f;
    #pragma unroll
    for (int c = 0; c < 16; ++c) s += F[qq*272 + ii + 16*c];
    s += __shfl_down(s, 8, 16);
    s += __shfl_down(s, 4, 16);
    s += __shfl_down(s, 2, 16);
    s += __shfl_down(s, 1, 16);
    if (ii == 0) atomicAdd(&out[b*NQ + qq], s);
}

extern "C" void kernel_launch(void* const* d_in, const int* in_sizes, int n_in,
                              void* d_out, int out_size, void* d_ws, size_t ws_size,
                              hipStream_t stream)
{
    (void)in_sizes; (void)n_in; (void)ws_size;
    const float* x      = (const float*)d_in[0];   // (512,16) fp32
    const float* params = (const float*)d_in[1];   // (4,16,3) fp32
    float* out = (float*)d_out;                    // (512,16) fp32
    f2* st = (f2*)d_ws;                            // 256 MiB state

    hipMemsetAsync(d_out, 0, (size_t)out_size * sizeof(float), stream);
    qc_B1_gen <<<dim3(512*8), dim3(TPB), 0, stream>>>(x, params, st);
    qc_A_lite <<<dim3(512*8), dim3(TPB), 0, stream>>>(params, st, 1);
    qc_B_heavy<<<dim3(512*8), dim3(TPB), 0, stream>>>(params, st, 2);
    qc_A_lite <<<dim3(512*8), dim3(TPB), 0, stream>>>(params, st, 2);
    qc_B_heavy<<<dim3(512*8), dim3(TPB), 0, stream>>>(params, st, 3);
    qc_A_final<<<dim3(512*8), dim3(TPB), 0, stream>>>(params, st, out);
}